// Round 16
// baseline (112.794 us; speedup 1.0000x reference)
//
#include <hip/hip_runtime.h>
#include <math.h>

// Problem constants
#define B_   32
#define N_   100
#define ND_  128   // NODE_DIM
#define ED_  64    // EDGE_DIM
#define HID_ 128
#define EPS_ 1e-5f
#define NNODE (B_*N_)                 // 3200
#define EDGE_SAMPLES ((float)(B_*N_*N_))  // 320000
#define LOG2E_ 1.4426950408889634f

#define MC_   7                       // m-rows per k2 block

// Workspace layout (in floats)
#define WS_A      0          // A  = h @ WA^T   [3200][128] f32
#define WS_PK     409600     // packed (bf16 Bv | bf16 hnb) [3200][128] uint
#define WS_HIN    819200     // h_in = h @ WU^T [3200][128] f32
#define WS_M      1638400    // m aggregation   [3200][128] f32
#define WS_STATS  2048000    // edge BN stats [32][2][128] (atomics)
#define WS_SCSH   (WS_STATS + 8192)   // (unused now; kept for layout stability)
#define WS_NSTB   (WS_SCSH + 256)     // node BN stats [32][2][128] (atomics)
#define ZERO_CNT  (8192 + 256 + 8192) // 16640

typedef __attribute__((ext_vector_type(8))) short bf16x8;
typedef __attribute__((ext_vector_type(4))) float f32x4;
#define MFMA16(a,b,c) __builtin_amdgcn_mfma_f32_16x16x32_bf16(a,b,c,0,0,0)

__device__ __forceinline__ unsigned short f2bf(float f) {
  unsigned int u = __float_as_uint(f);
  unsigned int r = (u + 0x7fffu + ((u >> 16) & 1u)) >> 16;
  return (unsigned short)r;
}

// load WC fragments for d-column d0 straight from global (L2-resident)
__device__ __forceinline__ void load_wc_frags(const float* __restrict__ WC,
                                              int d0, int lg, bf16x8 bfr[2]) {
#pragma unroll
  for (int kb = 0; kb < 2; ++kb) {
    const float* wrow = WC + d0 * 64 + kb * 32 + lg * 8;
    float4 u0 = *(const float4*)wrow;
    float4 u1 = *(const float4*)(wrow + 4);
    bf16x8 f;
    f[0] = (short)f2bf(u0.x); f[1] = (short)f2bf(u0.y);
    f[2] = (short)f2bf(u0.z); f[3] = (short)f2bf(u0.w);
    f[4] = (short)f2bf(u1.x); f[5] = (short)f2bf(u1.y);
    f[6] = (short)f2bf(u1.z); f[7] = (short)f2bf(u1.w);
    bfr[kb] = f;
  }
}

// ---------------------------------------------------------------------------
// K1: node projections via MFMA. grid (25, 4), block 256. 128 nodes/block.
//   y==0: WA -> WS_A (f32)        y==2: WU -> WS_HIN (f32)
//   y==1: WB -> WS_PK lo (bf16)   y==3: WV -> WS_PK hi (bf16)
// Also zeroes the stats accumulator regions (replaces hipMemsetAsync).
// ---------------------------------------------------------------------------
__global__ __launch_bounds__(256) void k1_proj(
    const float* __restrict__ h,
    const float* __restrict__ WA, const float* __restrict__ WB,
    const float* __restrict__ WU, const float* __restrict__ WV,
    float* __restrict__ ws) {
  __shared__ unsigned short h_lds[128 * 136];
  __shared__ unsigned short w_lds[128 * 136];
  const int t  = threadIdx.x;
  const int r0 = blockIdx.x * 128;
  const int y  = blockIdx.y;
  const float* W = (y == 0) ? WA : (y == 1) ? WB : (y == 2) ? WU : WV;

  {
    int gid = (y * 25 + blockIdx.x) * 256 + t;
    if (gid < ZERO_CNT) ws[WS_STATS + gid] = 0.f;
  }

  const float4* hp = (const float4*)(h + (size_t)r0 * 128);
  const float4* wp = (const float4*)W;
#pragma unroll
  for (int k = 0; k < 16; ++k) {
    int i = t + k * 256;
    int row = i >> 5, col = (i & 31) * 4;
    float4 v = hp[i];
    *(ushort4*)&h_lds[row * 136 + col] =
        make_ushort4(f2bf(v.x), f2bf(v.y), f2bf(v.z), f2bf(v.w));
    float4 u = wp[i];
    *(ushort4*)&w_lds[row * 136 + col] =
        make_ushort4(f2bf(u.x), f2bf(u.y), f2bf(u.z), f2bf(u.w));
  }
  __syncthreads();

  const int w  = t >> 6;
  const int l  = t & 63;
  const int lr = l & 15;
  const int lg = l >> 4;

  bf16x8 bfr[2][4];
#pragma unroll
  for (int nt = 0; nt < 2; ++nt) {
    int d = w * 32 + nt * 16 + lr;
#pragma unroll
    for (int kb = 0; kb < 4; ++kb)
      bfr[nt][kb] = *(const bf16x8*)&w_lds[d * 136 + kb * 32 + lg * 8];
  }

  f32x4 acc[8][2];
#pragma unroll
  for (int mt = 0; mt < 8; ++mt) { acc[mt][0] = (f32x4)0.f; acc[mt][1] = (f32x4)0.f; }

#pragma unroll
  for (int mt = 0; mt < 8; ++mt) {
    int row = mt * 16 + lr;
    bf16x8 af[4];
#pragma unroll
    for (int kb = 0; kb < 4; ++kb)
      af[kb] = *(const bf16x8*)&h_lds[row * 136 + kb * 32 + lg * 8];
#pragma unroll
    for (int nt = 0; nt < 2; ++nt)
#pragma unroll
      for (int kb = 0; kb < 4; ++kb)
        acc[mt][nt] = MFMA16(af[kb], bfr[nt][kb], acc[mt][nt]);
  }

  if (y == 0 || y == 2) {
    float* outp = ws + ((y == 0) ? WS_A : WS_HIN);
#pragma unroll
    for (int mt = 0; mt < 8; ++mt)
#pragma unroll
      for (int nt = 0; nt < 2; ++nt) {
        int dcol = w * 32 + nt * 16 + lr;
#pragma unroll
        for (int j = 0; j < 4; ++j) {
          int row = r0 + mt * 16 + lg * 4 + j;
          outp[row * 128 + dcol] = acc[mt][nt][j];
        }
      }
  } else {
    unsigned short* pks = (unsigned short*)(ws + WS_PK);
    const int half = (y == 1) ? 0 : 1;
#pragma unroll
    for (int mt = 0; mt < 8; ++mt)
#pragma unroll
      for (int nt = 0; nt < 2; ++nt) {
        int dcol = w * 32 + nt * 16 + lr;
#pragma unroll
        for (int j = 0; j < 4; ++j) {
          int row = r0 + mt * 16 + lg * 4 + j;
          pks[(row * 128 + dcol) * 2 + half] = f2bf(acc[mt][nt][j]);
        }
      }
  }
}

// ---------------------------------------------------------------------------
// K2: edge BN stats. grid (32, 15), block 256. One b, MC_ m-rows per block.
// Bv kept PACKED in 28+28 uint regs; e rows double-buffered in LDS.
// (R9-proven structure — do not restructure; see R6/R7/R10/R11 regressions.)
// ---------------------------------------------------------------------------
__global__ __launch_bounds__(256, 1) void k2_stats(
    const float* __restrict__ e, const float* __restrict__ WC,
    float* __restrict__ ws) {
  __shared__ unsigned short wc_lds[128 * 72];
  __shared__ unsigned short e_lds[2][112 * 72];
  const int t     = threadIdx.x;
  const int b     = blockIdx.x;
  const int chunk = blockIdx.y;
  const int m0    = chunk * MC_;
  const int mcnt  = min(MC_, N_ - m0);

  const float4* wcp = (const float4*)WC;
#pragma unroll
  for (int k = 0; k < 8; ++k) {
    int i = t + k * 256;
    float4 v = wcp[i];
    int row = i >> 4, col = (i & 15) * 4;
    *(ushort4*)&wc_lds[row * 72 + col] =
        make_ushort4(f2bf(v.x), f2bf(v.y), f2bf(v.z), f2bf(v.w));
  }
  for (int i = t; i < 12 * 72; i += 256) {
    e_lds[0][100 * 72 + i] = 0;
    e_lds[1][100 * 72 + i] = 0;
  }

  const int w  = t >> 6;
  const int l  = t & 63;
  const int lr = l & 15;
  const int lg = l >> 4;
  const int d0 = w * 32 + lr, d1 = d0 + 16;

  unsigned int pk0[7][4], pk1[7][4];
  const unsigned int* pkp = (const unsigned int*)(ws + WS_PK) + b * (N_ * 128);
#pragma unroll
  for (int mt = 0; mt < 7; ++mt)
#pragma unroll
    for (int j = 0; j < 4; ++j) {
      int node = mt * 16 + lg * 4 + j;
      bool ok = node < N_;
      pk0[mt][j] = ok ? pkp[node * 128 + d0] : 0u;
      pk1[mt][j] = ok ? pkp[node * 128 + d1] : 0u;
    }
  __syncthreads();

  bf16x8 bfr[2][2];
#pragma unroll
  for (int nt = 0; nt < 2; ++nt) {
    int d = w * 32 + nt * 16 + lr;
#pragma unroll
    for (int kb = 0; kb < 2; ++kb)
      bfr[nt][kb] = *(const bf16x8*)&wc_lds[d * 72 + kb * 32 + lg * 8];
  }

  float4 ld[7];
  {
    const float4* epf4 = (const float4*)(e + (size_t)(b * N_ + m0) * (N_ * ED_));
#pragma unroll
    for (int k = 0; k < 7; ++k) { int i = t + k * 256; if (i < 1600) ld[k] = epf4[i]; }
  }

  float s0 = 0.f, ss0 = 0.f, s1 = 0.f, ss1 = 0.f;
  int buf = 0;
  for (int r = 0; r < mcnt; ++r) {
#pragma unroll
    for (int k = 0; k < 7; ++k) {
      int i = t + k * 256;
      if (i < 1600) {
        float4 v = ld[k];
        int row = i >> 4, col = (i & 15) * 4;
        *(ushort4*)&e_lds[buf][row * 72 + col] =
            make_ushort4(f2bf(v.x), f2bf(v.y), f2bf(v.z), f2bf(v.w));
      }
    }
    __syncthreads();
    if (r + 1 < mcnt) {
      const float4* nxt = (const float4*)(e + (size_t)(b * N_ + m0 + r + 1) * (N_ * ED_));
#pragma unroll
      for (int k = 0; k < 7; ++k) { int i = t + k * 256; if (i < 1600) ld[k] = nxt[i]; }
    }

    const int bm = b * N_ + m0 + r;
    const float A0 = ws[WS_A + bm * 128 + d0];
    const float A1 = ws[WS_A + bm * 128 + d1];

    f32x4 acc[7][2];
#pragma unroll
    for (int mt = 0; mt < 7; ++mt) { acc[mt][0] = (f32x4)0.f; acc[mt][1] = (f32x4)0.f; }
#pragma unroll
    for (int mt = 0; mt < 7; ++mt) {
      int row = mt * 16 + lr;
      bf16x8 af0 = *(const bf16x8*)&e_lds[buf][row * 72 + lg * 8];
      bf16x8 af1 = *(const bf16x8*)&e_lds[buf][row * 72 + 32 + lg * 8];
#pragma unroll
      for (int nt = 0; nt < 2; ++nt) {
        acc[mt][nt] = MFMA16(af0, bfr[nt][0], acc[mt][nt]);
        acc[mt][nt] = MFMA16(af1, bfr[nt][1], acc[mt][nt]);
      }
    }

#pragma unroll
    for (int mt = 0; mt < 7; ++mt)
#pragma unroll
      for (int j = 0; j < 4; ++j) {
        int node = mt * 16 + lg * 4 + j;
        if (node < N_) {
          float x0 = acc[mt][0][j] + A0 + __uint_as_float(pk0[mt][j] << 16);
          float x1 = acc[mt][1][j] + A1 + __uint_as_float(pk1[mt][j] << 16);
          s0 += x0; ss0 += x0 * x0;
          s1 += x1; ss1 += x1 * x1;
        }
      }
    buf ^= 1;
  }

  s0 += __shfl_xor(s0, 16);  s0 += __shfl_xor(s0, 32);
  ss0 += __shfl_xor(ss0, 16); ss0 += __shfl_xor(ss0, 32);
  s1 += __shfl_xor(s1, 16);  s1 += __shfl_xor(s1, 32);
  ss1 += __shfl_xor(ss1, 16); ss1 += __shfl_xor(ss1, 32);
  if (l < 16) {
    atomicAdd(&ws[WS_STATS + b * 256 + d0], s0);
    atomicAdd(&ws[WS_STATS + b * 256 + 128 + d0], ss0);
    atomicAdd(&ws[WS_STATS + b * 256 + d1], s1);
    atomicAdd(&ws[WS_STATS + b * 256 + 128 + d1], ss1);
  }
}

// ---------------------------------------------------------------------------
// K4: main fused pass. grid 3200, block 512 (8 waves; wave w owns d-cols
// [16w,16w+16)). R9 structure + k0 FOLDED IN: each block redundantly reduces
// the 32-slot edge-BN stats table into LDS scale/shift during its preamble
// (hidden under e-staging; bitwise-deterministic across blocks). One less
// launch + gap. Fast epilogue; per-b node-BN stats fused.
// ---------------------------------------------------------------------------
__global__ __launch_bounds__(512) void k4_main(
    const float* __restrict__ e, const float* __restrict__ adj,
    const float* __restrict__ WC,
    const float* __restrict__ gamma_e, const float* __restrict__ beta_e,
    float* __restrict__ ws, float* __restrict__ out_enorm) {
  __shared__ unsigned short e_lds[112 * 72];   // 15.75 KB
  __shared__ float adj_lds[112];
  __shared__ float sc_l[128], sh_l[128];
  const int t  = threadIdx.x;
  const int bm = blockIdx.x;
  const int b  = bm / N_;
  const int w  = t >> 6;
  const int l  = t & 63;
  const int lr = l & 15;
  const int lg = l >> 4;
  const int d0 = w * 16 + lr;

  // (1) issue e loads
  float4 ld[4];
  const float4* ef4 = (const float4*)(e + (size_t)bm * (N_ * ED_));
#pragma unroll
  for (int k = 0; k < 4; ++k) { int i = t + k * 512; if (i < 1600) ld[k] = ef4[i]; }

  // (2) issue independent preloads: packed Bv/hnb, A, WC frags
  unsigned int pk[7][4];
  const unsigned int* pkp = (const unsigned int*)(ws + WS_PK) + b * (N_ * 128);
#pragma unroll
  for (int mt = 0; mt < 7; ++mt)
#pragma unroll
    for (int j = 0; j < 4; ++j) {
      int node = mt * 16 + lg * 4 + j;
      pk[mt][j] = (node < N_) ? pkp[node * 128 + d0] : 0u;
    }
  const float A0 = ws[WS_A + bm * 128 + d0];

  bf16x8 bfr[2];
  load_wc_frags(WC, d0, lg, bfr);

  if (t < 112) adj_lds[t] = (t < N_) ? adj[bm * N_ + t] : 0.f;

  // (2b) folded k0: reduce stats table -> scale/shift in LDS (t<128 only;
  // L2-hit loads, hidden under the staging all 512 threads are doing)
  if (t < 128) {
    float S = 0.f, SS = 0.f;
#pragma unroll
    for (int j = 0; j < 32; ++j) {
      S  += ws[WS_STATS + j * 256 + t];
      SS += ws[WS_STATS + j * 256 + 128 + t];
    }
    float mean = S * (1.0f / EDGE_SAMPLES);
    float var  = SS * (1.0f / EDGE_SAMPLES) - mean * mean;
    float sc   = gamma_e[t] * rsqrtf(var + EPS_);
    sc_l[t] = sc;
    sh_l[t] = beta_e[t] - mean * sc;
  }

  // (3) stage e -> LDS (bf16)
#pragma unroll
  for (int k = 0; k < 4; ++k) {
    int i = t + k * 512;
    if (i < 1600) {
      float4 v = ld[k];
      int row = i >> 4, col = (i & 15) * 4;
      *(ushort4*)&e_lds[row * 72 + col] =
          make_ushort4(f2bf(v.x), f2bf(v.y), f2bf(v.z), f2bf(v.w));
    }
  }
  for (int i = t; i < 12 * 72; i += 512) e_lds[100 * 72 + i] = 0;
  __syncthreads();

  const float sc0 = sc_l[d0];
  const float sh0 = sh_l[d0];

  // (4) GEMM: 14 MFMAs per wave
  f32x4 acc[7];
#pragma unroll
  for (int mt = 0; mt < 7; ++mt) {
    int row = mt * 16 + lr;
    bf16x8 af0 = *(const bf16x8*)&e_lds[row * 72 + lg * 8];
    bf16x8 af1 = *(const bf16x8*)&e_lds[row * 72 + 32 + lg * 8];
    f32x4 a = (f32x4)0.f;
    a = MFMA16(af0, bfr[0], a);
    a = MFMA16(af1, bfr[1], a);
    acc[mt] = a;
  }

  // (5) epilogue: BN -> relu -> *adj -> sigmoid -> exp (no predication)
  float den = 0.f;
#pragma unroll
  for (int mt = 0; mt < 7; ++mt)
#pragma unroll
    for (int j = 0; j < 4; ++j) {
      int node = mt * 16 + lg * 4 + j;
      float bv = __uint_as_float(pk[mt][j] << 16);
      float x  = (acc[mt][j] + A0 + bv) * sc0 + sh0;
      float r  = fmaxf(x, 0.f) * adj_lds[node];
      float en = __builtin_amdgcn_exp2f(r * -LOG2E_);
      float sg = __builtin_amdgcn_rcpf(1.f + en);
      float p  = __builtin_amdgcn_exp2f(sg * LOG2E_);
      acc[mt][j] = p; den += p;
    }
  den += __shfl_xor(den, 16); den += __shfl_xor(den, 32);
  // pad rows (zero e, adj=0) each contributed exactly exp2(0.5*log2e)
  den -= 12.f * __builtin_amdgcn_exp2f(0.5f * LOG2E_);
  const float rc = __builtin_amdgcn_rcpf(den);

  // (6) normalize, write e_norm, aggregate m
  float msg = 0.f;
  float* outp = out_enorm + (size_t)bm * (N_ * 128);
#pragma unroll
  for (int mt = 0; mt < 7; ++mt)
#pragma unroll
    for (int j = 0; j < 4; ++j) {
      int node = mt * 16 + lg * 4 + j;
      if (node < N_) {
        float v = acc[mt][j] * rc;
        outp[node * 128 + d0] = v;
        float hn = __uint_as_float(pk[mt][j] & 0xffff0000u);
        msg += v * hn;
      }
    }
  msg += __shfl_xor(msg, 16); msg += __shfl_xor(msg, 32);
  if (l < 16) {
    ws[WS_M + bm * 128 + d0] = msg;
    atomicAdd(&ws[WS_NSTB + b * 256 + d0],       msg);
    atomicAdd(&ws[WS_NSTB + b * 256 + 128 + d0], msg * msg);
  }
}

// ---------------------------------------------------------------------------
// K5b: finalize node BN (32-slot reduce) + h_out. grid 1600, block 256.
// ---------------------------------------------------------------------------
__global__ __launch_bounds__(256) void k5b_hout(
    const float* __restrict__ gamma_n, const float* __restrict__ beta_n,
    const float* __restrict__ ws, float* __restrict__ hout) {
  __shared__ float sc_l[128], sh_l[128];
  const int t = threadIdx.x;
  if (t < 128) {
    float S = 0.f, SS = 0.f;
#pragma unroll
    for (int j = 0; j < 32; ++j) {
      S  += ws[WS_NSTB + j * 256 + t];
      SS += ws[WS_NSTB + j * 256 + 128 + t];
    }
    float mean = S * (1.0f / (float)NNODE);
    float var  = SS * (1.0f / (float)NNODE) - mean * mean;
    float sc   = gamma_n[t] * rsqrtf(var + EPS_);
    sc_l[t] = sc;
    sh_l[t] = beta_n[t] - mean * sc;
  }
  __syncthreads();
  const int idx = blockIdx.x * 256 + t;   // < 409600
  const int d = t & 127;
  float mv = ws[WS_M + idx];
  hout[idx] = ws[WS_HIN + idx] + fmaxf(mv * sc_l[d] + sh_l[d], 0.f);
}

// ---------------------------------------------------------------------------
extern "C" void kernel_launch(void* const* d_in, const int* in_sizes, int n_in,
                              void* d_out, int out_size, void* d_ws, size_t ws_size,
                              hipStream_t stream) {
  (void)in_sizes; (void)n_in; (void)out_size; (void)ws_size;
  const float* h   = (const float*)d_in[0];
  const float* e   = (const float*)d_in[1];
  const float* adj = (const float*)d_in[2];
  const float* WU  = (const float*)d_in[3];
  const float* WV  = (const float*)d_in[4];
  const float* WA  = (const float*)d_in[5];
  const float* WB  = (const float*)d_in[6];
  const float* WC  = (const float*)d_in[7];
  const float* geg = (const float*)d_in[8];
  const float* geb = (const float*)d_in[9];
  const float* gng = (const float*)d_in[10];
  const float* gnb = (const float*)d_in[11];

  float* out = (float*)d_out;   // h_out [409600] then e_norm [40960000]
  float* ws  = (float*)d_ws;

  k1_proj <<<dim3(25, 4),  256, 0, stream>>>(h, WA, WB, WU, WV, ws);
  k2_stats<<<dim3(32, 15), 256, 0, stream>>>(e, WC, ws);
  k4_main <<<3200,         512, 0, stream>>>(e, adj, WC, geg, geb, ws, out + 409600);
  k5b_hout<<<1600,         256, 0, stream>>>(gng, gnb, ws, out);
}

// Round 17
// 88.787 us; speedup vs baseline: 1.2704x; 1.2704x over previous
//
#include <hip/hip_runtime.h>
#include <math.h>

// Problem constants
#define B_   32
#define N_   100
#define ND_  128   // NODE_DIM
#define ED_  64    // EDGE_DIM
#define HID_ 128
#define EPS_ 1e-5f
#define NNODE (B_*N_)                 // 3200
#define EDGE_SAMPLES ((float)(B_*N_*N_))  // 320000
#define LOG2E_ 1.4426950408889634f

#define MC_   7                       // m-rows per k2 block

// Workspace layout (in floats)
#define WS_A      0          // A  = h @ WA^T   [3200][128] f32
#define WS_PK     409600     // packed (bf16 Bv | bf16 hnb) [3200][128] uint
#define WS_HIN    819200     // h_in = h @ WU^T [3200][128] f32
#define WS_M      1638400    // m aggregation   [3200][128] f32
#define WS_STATS  2048000    // edge BN stats [32][2][128] (atomics)
#define WS_SCSH   (WS_STATS + 8192)   // edge BN scale/shift [2][128]
#define WS_NSTB   (WS_SCSH + 256)     // node BN stats [32][2][128] (atomics)
#define ZERO_CNT  (8192 + 256 + 8192) // 16640

typedef __attribute__((ext_vector_type(8))) short bf16x8;
typedef __attribute__((ext_vector_type(4))) float f32x4;
#define MFMA16(a,b,c) __builtin_amdgcn_mfma_f32_16x16x32_bf16(a,b,c,0,0,0)

__device__ __forceinline__ unsigned short f2bf(float f) {
  unsigned int u = __float_as_uint(f);
  unsigned int r = (u + 0x7fffu + ((u >> 16) & 1u)) >> 16;
  return (unsigned short)r;
}

// ---------------------------------------------------------------------------
// K1: node projections via MFMA. grid (25, 4), block 256. 128 nodes/block.
//   y==0: WA -> WS_A (f32)        y==2: WU -> WS_HIN (f32)
//   y==1: WB -> WS_PK lo (bf16)   y==3: WV -> WS_PK hi (bf16)
// Also zeroes the stats accumulator regions (replaces hipMemsetAsync).
// ---------------------------------------------------------------------------
__global__ __launch_bounds__(256) void k1_proj(
    const float* __restrict__ h,
    const float* __restrict__ WA, const float* __restrict__ WB,
    const float* __restrict__ WU, const float* __restrict__ WV,
    float* __restrict__ ws) {
  __shared__ unsigned short h_lds[128 * 136];
  __shared__ unsigned short w_lds[128 * 136];
  const int t  = threadIdx.x;
  const int r0 = blockIdx.x * 128;
  const int y  = blockIdx.y;
  const float* W = (y == 0) ? WA : (y == 1) ? WB : (y == 2) ? WU : WV;

  {
    int gid = (y * 25 + blockIdx.x) * 256 + t;
    if (gid < ZERO_CNT) ws[WS_STATS + gid] = 0.f;
  }

  const float4* hp = (const float4*)(h + (size_t)r0 * 128);
  const float4* wp = (const float4*)W;
#pragma unroll
  for (int k = 0; k < 16; ++k) {
    int i = t + k * 256;
    int row = i >> 5, col = (i & 31) * 4;
    float4 v = hp[i];
    *(ushort4*)&h_lds[row * 136 + col] =
        make_ushort4(f2bf(v.x), f2bf(v.y), f2bf(v.z), f2bf(v.w));
    float4 u = wp[i];
    *(ushort4*)&w_lds[row * 136 + col] =
        make_ushort4(f2bf(u.x), f2bf(u.y), f2bf(u.z), f2bf(u.w));
  }
  __syncthreads();

  const int w  = t >> 6;
  const int l  = t & 63;
  const int lr = l & 15;
  const int lg = l >> 4;

  bf16x8 bfr[2][4];
#pragma unroll
  for (int nt = 0; nt < 2; ++nt) {
    int d = w * 32 + nt * 16 + lr;
#pragma unroll
    for (int kb = 0; kb < 4; ++kb)
      bfr[nt][kb] = *(const bf16x8*)&w_lds[d * 136 + kb * 32 + lg * 8];
  }

  f32x4 acc[8][2];
#pragma unroll
  for (int mt = 0; mt < 8; ++mt) { acc[mt][0] = (f32x4)0.f; acc[mt][1] = (f32x4)0.f; }

#pragma unroll
  for (int mt = 0; mt < 8; ++mt) {
    int row = mt * 16 + lr;
    bf16x8 af[4];
#pragma unroll
    for (int kb = 0; kb < 4; ++kb)
      af[kb] = *(const bf16x8*)&h_lds[row * 136 + kb * 32 + lg * 8];
#pragma unroll
    for (int nt = 0; nt < 2; ++nt)
#pragma unroll
      for (int kb = 0; kb < 4; ++kb)
        acc[mt][nt] = MFMA16(af[kb], bfr[nt][kb], acc[mt][nt]);
  }

  if (y == 0 || y == 2) {
    float* outp = ws + ((y == 0) ? WS_A : WS_HIN);
#pragma unroll
    for (int mt = 0; mt < 8; ++mt)
#pragma unroll
      for (int nt = 0; nt < 2; ++nt) {
        int dcol = w * 32 + nt * 16 + lr;
#pragma unroll
        for (int j = 0; j < 4; ++j) {
          int row = r0 + mt * 16 + lg * 4 + j;
          outp[row * 128 + dcol] = acc[mt][nt][j];
        }
      }
  } else {
    unsigned short* pks = (unsigned short*)(ws + WS_PK);
    const int half = (y == 1) ? 0 : 1;
#pragma unroll
    for (int mt = 0; mt < 8; ++mt)
#pragma unroll
      for (int nt = 0; nt < 2; ++nt) {
        int dcol = w * 32 + nt * 16 + lr;
#pragma unroll
        for (int j = 0; j < 4; ++j) {
          int row = r0 + mt * 16 + lg * 4 + j;
          pks[(row * 128 + dcol) * 2 + half] = f2bf(acc[mt][nt][j]);
        }
      }
  }
}

// ---------------------------------------------------------------------------
// K2: edge BN stats. grid (32, 15), block 256. One b, MC_ m-rows per block.
// Bv kept PACKED in 28+28 uint regs; e rows double-buffered in LDS.
// (Proven structure — do not restructure; see R6/R7/R10/R11 regressions.)
// ---------------------------------------------------------------------------
__global__ __launch_bounds__(256, 1) void k2_stats(
    const float* __restrict__ e, const float* __restrict__ WC,
    float* __restrict__ ws) {
  __shared__ unsigned short wc_lds[128 * 72];
  __shared__ unsigned short e_lds[2][112 * 72];
  const int t     = threadIdx.x;
  const int b     = blockIdx.x;
  const int chunk = blockIdx.y;
  const int m0    = chunk * MC_;
  const int mcnt  = min(MC_, N_ - m0);

  const float4* wcp = (const float4*)WC;
#pragma unroll
  for (int k = 0; k < 8; ++k) {
    int i = t + k * 256;
    float4 v = wcp[i];
    int row = i >> 4, col = (i & 15) * 4;
    *(ushort4*)&wc_lds[row * 72 + col] =
        make_ushort4(f2bf(v.x), f2bf(v.y), f2bf(v.z), f2bf(v.w));
  }
  for (int i = t; i < 12 * 72; i += 256) {
    e_lds[0][100 * 72 + i] = 0;
    e_lds[1][100 * 72 + i] = 0;
  }

  const int w  = t >> 6;
  const int l  = t & 63;
  const int lr = l & 15;
  const int lg = l >> 4;
  const int d0 = w * 32 + lr, d1 = d0 + 16;

  unsigned int pk0[7][4], pk1[7][4];
  const unsigned int* pkp = (const unsigned int*)(ws + WS_PK) + b * (N_ * 128);
#pragma unroll
  for (int mt = 0; mt < 7; ++mt)
#pragma unroll
    for (int j = 0; j < 4; ++j) {
      int node = mt * 16 + lg * 4 + j;
      bool ok = node < N_;
      pk0[mt][j] = ok ? pkp[node * 128 + d0] : 0u;
      pk1[mt][j] = ok ? pkp[node * 128 + d1] : 0u;
    }
  __syncthreads();

  bf16x8 bfr[2][2];
#pragma unroll
  for (int nt = 0; nt < 2; ++nt) {
    int d = w * 32 + nt * 16 + lr;
#pragma unroll
    for (int kb = 0; kb < 2; ++kb)
      bfr[nt][kb] = *(const bf16x8*)&wc_lds[d * 72 + kb * 32 + lg * 8];
  }

  float4 ld[7];
  {
    const float4* epf4 = (const float4*)(e + (size_t)(b * N_ + m0) * (N_ * ED_));
#pragma unroll
    for (int k = 0; k < 7; ++k) { int i = t + k * 256; if (i < 1600) ld[k] = epf4[i]; }
  }

  float s0 = 0.f, ss0 = 0.f, s1 = 0.f, ss1 = 0.f;
  int buf = 0;
  for (int r = 0; r < mcnt; ++r) {
#pragma unroll
    for (int k = 0; k < 7; ++k) {
      int i = t + k * 256;
      if (i < 1600) {
        float4 v = ld[k];
        int row = i >> 4, col = (i & 15) * 4;
        *(ushort4*)&e_lds[buf][row * 72 + col] =
            make_ushort4(f2bf(v.x), f2bf(v.y), f2bf(v.z), f2bf(v.w));
      }
    }
    __syncthreads();
    if (r + 1 < mcnt) {
      const float4* nxt = (const float4*)(e + (size_t)(b * N_ + m0 + r + 1) * (N_ * ED_));
#pragma unroll
      for (int k = 0; k < 7; ++k) { int i = t + k * 256; if (i < 1600) ld[k] = nxt[i]; }
    }

    const int bm = b * N_ + m0 + r;
    const float A0 = ws[WS_A + bm * 128 + d0];
    const float A1 = ws[WS_A + bm * 128 + d1];

    f32x4 acc[7][2];
#pragma unroll
    for (int mt = 0; mt < 7; ++mt) { acc[mt][0] = (f32x4)0.f; acc[mt][1] = (f32x4)0.f; }
#pragma unroll
    for (int mt = 0; mt < 7; ++mt) {
      int row = mt * 16 + lr;
      bf16x8 af0 = *(const bf16x8*)&e_lds[buf][row * 72 + lg * 8];
      bf16x8 af1 = *(const bf16x8*)&e_lds[buf][row * 72 + 32 + lg * 8];
#pragma unroll
      for (int nt = 0; nt < 2; ++nt) {
        acc[mt][nt] = MFMA16(af0, bfr[nt][0], acc[mt][nt]);
        acc[mt][nt] = MFMA16(af1, bfr[nt][1], acc[mt][nt]);
      }
    }

#pragma unroll
    for (int mt = 0; mt < 7; ++mt)
#pragma unroll
      for (int j = 0; j < 4; ++j) {
        int node = mt * 16 + lg * 4 + j;
        if (node < N_) {
          float x0 = acc[mt][0][j] + A0 + __uint_as_float(pk0[mt][j] << 16);
          float x1 = acc[mt][1][j] + A1 + __uint_as_float(pk1[mt][j] << 16);
          s0 += x0; ss0 += x0 * x0;
          s1 += x1; ss1 += x1 * x1;
        }
      }
    buf ^= 1;
  }

  s0 += __shfl_xor(s0, 16);  s0 += __shfl_xor(s0, 32);
  ss0 += __shfl_xor(ss0, 16); ss0 += __shfl_xor(ss0, 32);
  s1 += __shfl_xor(s1, 16);  s1 += __shfl_xor(s1, 32);
  ss1 += __shfl_xor(ss1, 16); ss1 += __shfl_xor(ss1, 32);
  if (l < 16) {
    atomicAdd(&ws[WS_STATS + b * 256 + d0], s0);
    atomicAdd(&ws[WS_STATS + b * 256 + 128 + d0], ss0);
    atomicAdd(&ws[WS_STATS + b * 256 + d1], s1);
    atomicAdd(&ws[WS_STATS + b * 256 + 128 + d1], ss1);
  }
}

// ---------------------------------------------------------------------------
// K0: finalize edge BN -> scale/shift (one block, 128 threads)
// ---------------------------------------------------------------------------
__global__ __launch_bounds__(128) void k0_finalize(
    const float* __restrict__ gamma_e, const float* __restrict__ beta_e,
    float* __restrict__ ws) {
  const int t = threadIdx.x;
  float S = 0.f, SS = 0.f;
#pragma unroll
  for (int j = 0; j < 32; ++j) {
    S  += ws[WS_STATS + j * 256 + t];
    SS += ws[WS_STATS + j * 256 + 128 + t];
  }
  float mean = S * (1.0f / EDGE_SAMPLES);
  float var  = SS * (1.0f / EDGE_SAMPLES) - mean * mean;
  float sc   = gamma_e[t] * rsqrtf(var + EPS_);
  ws[WS_SCSH + t]       = sc;
  ws[WS_SCSH + 128 + t] = beta_e[t] - mean * sc;
}

// ---------------------------------------------------------------------------
// K4: main fused pass. grid 3200, block 512 (8 waves; wave w owns d-cols
// [16w,16w+16)). Direct-global WC fragments; packed bf16 Bv/hnb preloads
// issued before the staging barrier; e staged in LDS. Fast epilogue
// (hw rcp/exp2), predication-free math loop. Per-b node-BN stats fused.
// ---------------------------------------------------------------------------
__global__ __launch_bounds__(512) void k4_main(
    const float* __restrict__ e, const float* __restrict__ adj,
    const float* __restrict__ WC,
    float* __restrict__ ws, float* __restrict__ out_enorm) {
  __shared__ unsigned short e_lds[112 * 72];   // 15.75 KB
  __shared__ float adj_lds[112];
  const int t  = threadIdx.x;
  const int bm = blockIdx.x;
  const int b  = bm / N_;
  const int w  = t >> 6;
  const int l  = t & 63;
  const int lr = l & 15;
  const int lg = l >> 4;
  const int d0 = w * 16 + lr;

  // (1) issue e loads
  float4 ld[4];
  const float4* ef4 = (const float4*)(e + (size_t)bm * (N_ * ED_));
#pragma unroll
  for (int k = 0; k < 4; ++k) { int i = t + k * 512; if (i < 1600) ld[k] = ef4[i]; }

  // (2) issue independent preloads: packed Bv/hnb, A, scale/shift, WC frags
  unsigned int pk[7][4];
  const unsigned int* pkp = (const unsigned int*)(ws + WS_PK) + b * (N_ * 128);
#pragma unroll
  for (int mt = 0; mt < 7; ++mt)
#pragma unroll
    for (int j = 0; j < 4; ++j) {
      int node = mt * 16 + lg * 4 + j;
      pk[mt][j] = (node < N_) ? pkp[node * 128 + d0] : 0u;
    }
  const float A0  = ws[WS_A + bm * 128 + d0];
  const float sc0 = ws[WS_SCSH + d0];
  const float sh0 = ws[WS_SCSH + 128 + d0];

  bf16x8 bfr[2];
#pragma unroll
  for (int kb = 0; kb < 2; ++kb) {
    const float* wrow = WC + d0 * 64 + kb * 32 + lg * 8;
    float4 u0 = *(const float4*)wrow;
    float4 u1 = *(const float4*)(wrow + 4);
    bf16x8 f;
    f[0] = (short)f2bf(u0.x); f[1] = (short)f2bf(u0.y);
    f[2] = (short)f2bf(u0.z); f[3] = (short)f2bf(u0.w);
    f[4] = (short)f2bf(u1.x); f[5] = (short)f2bf(u1.y);
    f[6] = (short)f2bf(u1.z); f[7] = (short)f2bf(u1.w);
    bfr[kb] = f;
  }

  if (t < 112) adj_lds[t] = (t < N_) ? adj[bm * N_ + t] : 0.f;

  // (3) stage e -> LDS (bf16)
#pragma unroll
  for (int k = 0; k < 4; ++k) {
    int i = t + k * 512;
    if (i < 1600) {
      float4 v = ld[k];
      int row = i >> 4, col = (i & 15) * 4;
      *(ushort4*)&e_lds[row * 72 + col] =
          make_ushort4(f2bf(v.x), f2bf(v.y), f2bf(v.z), f2bf(v.w));
    }
  }
  for (int i = t; i < 12 * 72; i += 512) e_lds[100 * 72 + i] = 0;
  __syncthreads();

  // (4) GEMM: 14 MFMAs per wave
  f32x4 acc[7];
#pragma unroll
  for (int mt = 0; mt < 7; ++mt) acc[mt] = (f32x4)0.f;
#pragma unroll
  for (int mt = 0; mt < 7; ++mt) {
    int row = mt * 16 + lr;
    bf16x8 af0 = *(const bf16x8*)&e_lds[row * 72 + lg * 8];
    bf16x8 af1 = *(const bf16x8*)&e_lds[row * 72 + 32 + lg * 8];
    acc[mt] = MFMA16(af0, bfr[0], acc[mt]);
    acc[mt] = MFMA16(af1, bfr[1], acc[mt]);
  }

  // (5) epilogue: BN -> relu -> *adj -> sigmoid -> exp (no predication)
  float den = 0.f;
#pragma unroll
  for (int mt = 0; mt < 7; ++mt)
#pragma unroll
    for (int j = 0; j < 4; ++j) {
      int node = mt * 16 + lg * 4 + j;
      float bv = __uint_as_float(pk[mt][j] << 16);
      float x  = (acc[mt][j] + A0 + bv) * sc0 + sh0;
      float r  = fmaxf(x, 0.f) * adj_lds[node];
      float en = __builtin_amdgcn_exp2f(r * -LOG2E_);
      float sg = __builtin_amdgcn_rcpf(1.f + en);
      float p  = __builtin_amdgcn_exp2f(sg * LOG2E_);
      acc[mt][j] = p; den += p;
    }
  den += __shfl_xor(den, 16); den += __shfl_xor(den, 32);
  // pad rows (zero e, adj=0) each contributed exactly exp2(0.5*log2e)
  den -= 12.f * __builtin_amdgcn_exp2f(0.5f * LOG2E_);
  const float rc = __builtin_amdgcn_rcpf(den);

  // (6) normalize, write e_norm, aggregate m
  float msg = 0.f;
  float* outp = out_enorm + (size_t)bm * (N_ * 128);
#pragma unroll
  for (int mt = 0; mt < 7; ++mt)
#pragma unroll
    for (int j = 0; j < 4; ++j) {
      int node = mt * 16 + lg * 4 + j;
      if (node < N_) {
        float v = acc[mt][j] * rc;
        outp[node * 128 + d0] = v;
        float hn = __uint_as_float(pk[mt][j] & 0xffff0000u);
        msg += v * hn;
      }
    }
  msg += __shfl_xor(msg, 16); msg += __shfl_xor(msg, 32);
  if (l < 16) {
    ws[WS_M + bm * 128 + d0] = msg;
    atomicAdd(&ws[WS_NSTB + b * 256 + d0],       msg);
    atomicAdd(&ws[WS_NSTB + b * 256 + 128 + d0], msg * msg);
  }
}

// ---------------------------------------------------------------------------
// K5b: finalize node BN (32-slot reduce) + h_out. grid 1600, block 256.
// ---------------------------------------------------------------------------
__global__ __launch_bounds__(256) void k5b_hout(
    const float* __restrict__ gamma_n, const float* __restrict__ beta_n,
    const float* __restrict__ ws, float* __restrict__ hout) {
  __shared__ float sc_l[128], sh_l[128];
  const int t = threadIdx.x;
  if (t < 128) {
    float S = 0.f, SS = 0.f;
#pragma unroll
    for (int j = 0; j < 32; ++j) {
      S  += ws[WS_NSTB + j * 256 + t];
      SS += ws[WS_NSTB + j * 256 + 128 + t];
    }
    float mean = S * (1.0f / (float)NNODE);
    float var  = SS * (1.0f / (float)NNODE) - mean * mean;
    float sc   = gamma_n[t] * rsqrtf(var + EPS_);
    sc_l[t] = sc;
    sh_l[t] = beta_n[t] - mean * sc;
  }
  __syncthreads();
  const int idx = blockIdx.x * 256 + t;   // < 409600
  const int d = t & 127;
  float mv = ws[WS_M + idx];
  hout[idx] = ws[WS_HIN + idx] + fmaxf(mv * sc_l[d] + sh_l[d], 0.f);
}

// ---------------------------------------------------------------------------
extern "C" void kernel_launch(void* const* d_in, const int* in_sizes, int n_in,
                              void* d_out, int out_size, void* d_ws, size_t ws_size,
                              hipStream_t stream) {
  (void)in_sizes; (void)n_in; (void)out_size; (void)ws_size;
  const float* h   = (const float*)d_in[0];
  const float* e   = (const float*)d_in[1];
  const float* adj = (const float*)d_in[2];
  const float* WU  = (const float*)d_in[3];
  const float* WV  = (const float*)d_in[4];
  const float* WA  = (const float*)d_in[5];
  const float* WB  = (const float*)d_in[6];
  const float* WC  = (const float*)d_in[7];
  const float* geg = (const float*)d_in[8];
  const float* geb = (const float*)d_in[9];
  const float* gng = (const float*)d_in[10];
  const float* gnb = (const float*)d_in[11];

  float* out = (float*)d_out;   // h_out [409600] then e_norm [40960000]
  float* ws  = (float*)d_ws;

  k1_proj    <<<dim3(25, 4),  256, 0, stream>>>(h, WA, WB, WU, WV, ws);
  k2_stats   <<<dim3(32, 15), 256, 0, stream>>>(e, WC, ws);
  k0_finalize<<<1,            128, 0, stream>>>(geg, geb, ws);
  k4_main    <<<3200,         512, 0, stream>>>(e, adj, WC, ws, out + 409600);
  k5b_hout   <<<1600,         256, 0, stream>>>(gng, gnb, ws, out);
}

// Round 18
// 86.172 us; speedup vs baseline: 1.3090x; 1.0304x over previous
//
#include <hip/hip_runtime.h>
#include <math.h>

// Problem constants
#define B_   32
#define N_   100
#define ND_  128   // NODE_DIM
#define ED_  64    // EDGE_DIM
#define HID_ 128
#define EPS_ 1e-5f
#define NNODE (B_*N_)                 // 3200
#define EDGE_SAMPLES ((float)(B_*N_*N_))  // 320000
#define LOG2E_ 1.4426950408889634f

#define MC_   7                       // m-rows per k2 block

// Workspace layout (in floats)
#define WS_A      0          // A  = h @ WA^T   [3200][128] f32
#define WS_PK     409600     // packed (bf16 Bv | bf16 hnb) [3200][128] uint
#define WS_HIN    819200     // h_in = h @ WU^T [3200][128] f32
#define WS_M      1638400    // m aggregation   [3200][128] f32
#define WS_STATS  2048000    // edge BN stats [32][2][128] (atomics)
#define WS_SCSH   (WS_STATS + 8192)   // edge BN scale/shift [2][128]
#define WS_NSTB   (WS_SCSH + 256)     // node BN stats [32][2][128] (atomics)
#define ZERO_CNT  (8192 + 256 + 8192) // 16640

typedef __attribute__((ext_vector_type(8))) short bf16x8;
typedef __attribute__((ext_vector_type(4))) float f32x4;
#define MFMA16(a,b,c) __builtin_amdgcn_mfma_f32_16x16x32_bf16(a,b,c,0,0,0)

__device__ __forceinline__ unsigned short f2bf(float f) {
  unsigned int u = __float_as_uint(f);
  unsigned int r = (u + 0x7fffu + ((u >> 16) & 1u)) >> 16;
  return (unsigned short)r;
}

// ---------------------------------------------------------------------------
// K1: node projections via MFMA. grid (25, 4), block 256. 128 nodes/block.
//   y==0: WA -> WS_A (f32)        y==2: WU -> WS_HIN (f32)
//   y==1: WB -> WS_PK lo (bf16)   y==3: WV -> WS_PK hi (bf16)
// Also zeroes the stats accumulator regions (replaces hipMemsetAsync).
// ---------------------------------------------------------------------------
__global__ __launch_bounds__(256) void k1_proj(
    const float* __restrict__ h,
    const float* __restrict__ WA, const float* __restrict__ WB,
    const float* __restrict__ WU, const float* __restrict__ WV,
    float* __restrict__ ws) {
  __shared__ unsigned short h_lds[128 * 136];
  __shared__ unsigned short w_lds[128 * 136];
  const int t  = threadIdx.x;
  const int r0 = blockIdx.x * 128;
  const int y  = blockIdx.y;
  const float* W = (y == 0) ? WA : (y == 1) ? WB : (y == 2) ? WU : WV;

  {
    int gid = (y * 25 + blockIdx.x) * 256 + t;
    if (gid < ZERO_CNT) ws[WS_STATS + gid] = 0.f;
  }

  const float4* hp = (const float4*)(h + (size_t)r0 * 128);
  const float4* wp = (const float4*)W;
#pragma unroll
  for (int k = 0; k < 16; ++k) {
    int i = t + k * 256;
    int row = i >> 5, col = (i & 31) * 4;
    float4 v = hp[i];
    *(ushort4*)&h_lds[row * 136 + col] =
        make_ushort4(f2bf(v.x), f2bf(v.y), f2bf(v.z), f2bf(v.w));
    float4 u = wp[i];
    *(ushort4*)&w_lds[row * 136 + col] =
        make_ushort4(f2bf(u.x), f2bf(u.y), f2bf(u.z), f2bf(u.w));
  }
  __syncthreads();

  const int w  = t >> 6;
  const int l  = t & 63;
  const int lr = l & 15;
  const int lg = l >> 4;

  bf16x8 bfr[2][4];
#pragma unroll
  for (int nt = 0; nt < 2; ++nt) {
    int d = w * 32 + nt * 16 + lr;
#pragma unroll
    for (int kb = 0; kb < 4; ++kb)
      bfr[nt][kb] = *(const bf16x8*)&w_lds[d * 136 + kb * 32 + lg * 8];
  }

  f32x4 acc[8][2];
#pragma unroll
  for (int mt = 0; mt < 8; ++mt) { acc[mt][0] = (f32x4)0.f; acc[mt][1] = (f32x4)0.f; }

#pragma unroll
  for (int mt = 0; mt < 8; ++mt) {
    int row = mt * 16 + lr;
    bf16x8 af[4];
#pragma unroll
    for (int kb = 0; kb < 4; ++kb)
      af[kb] = *(const bf16x8*)&h_lds[row * 136 + kb * 32 + lg * 8];
#pragma unroll
    for (int nt = 0; nt < 2; ++nt)
#pragma unroll
      for (int kb = 0; kb < 4; ++kb)
        acc[mt][nt] = MFMA16(af[kb], bfr[nt][kb], acc[mt][nt]);
  }

  if (y == 0 || y == 2) {
    float* outp = ws + ((y == 0) ? WS_A : WS_HIN);
#pragma unroll
    for (int mt = 0; mt < 8; ++mt)
#pragma unroll
      for (int nt = 0; nt < 2; ++nt) {
        int dcol = w * 32 + nt * 16 + lr;
#pragma unroll
        for (int j = 0; j < 4; ++j) {
          int row = r0 + mt * 16 + lg * 4 + j;
          outp[row * 128 + dcol] = acc[mt][nt][j];
        }
      }
  } else {
    unsigned short* pks = (unsigned short*)(ws + WS_PK);
    const int half = (y == 1) ? 0 : 1;
#pragma unroll
    for (int mt = 0; mt < 8; ++mt)
#pragma unroll
      for (int nt = 0; nt < 2; ++nt) {
        int dcol = w * 32 + nt * 16 + lr;
#pragma unroll
        for (int j = 0; j < 4; ++j) {
          int row = r0 + mt * 16 + lg * 4 + j;
          pks[(row * 128 + dcol) * 2 + half] = f2bf(acc[mt][nt][j]);
        }
      }
  }
}

// ---------------------------------------------------------------------------
// K2: edge BN stats. grid (32, 15), block 256. One b, MC_ m-rows per block.
// Bv kept PACKED in 28+28 uint regs; e rows double-buffered in LDS.
// (Proven structure — do not restructure; see R6/R7/R10/R11 regressions.)
// ---------------------------------------------------------------------------
__global__ __launch_bounds__(256, 1) void k2_stats(
    const float* __restrict__ e, const float* __restrict__ WC,
    float* __restrict__ ws) {
  __shared__ unsigned short wc_lds[128 * 72];
  __shared__ unsigned short e_lds[2][112 * 72];
  const int t     = threadIdx.x;
  const int b     = blockIdx.x;
  const int chunk = blockIdx.y;
  const int m0    = chunk * MC_;
  const int mcnt  = min(MC_, N_ - m0);

  const float4* wcp = (const float4*)WC;
#pragma unroll
  for (int k = 0; k < 8; ++k) {
    int i = t + k * 256;
    float4 v = wcp[i];
    int row = i >> 4, col = (i & 15) * 4;
    *(ushort4*)&wc_lds[row * 72 + col] =
        make_ushort4(f2bf(v.x), f2bf(v.y), f2bf(v.z), f2bf(v.w));
  }
  for (int i = t; i < 12 * 72; i += 256) {
    e_lds[0][100 * 72 + i] = 0;
    e_lds[1][100 * 72 + i] = 0;
  }

  const int w  = t >> 6;
  const int l  = t & 63;
  const int lr = l & 15;
  const int lg = l >> 4;
  const int d0 = w * 32 + lr, d1 = d0 + 16;

  unsigned int pk0[7][4], pk1[7][4];
  const unsigned int* pkp = (const unsigned int*)(ws + WS_PK) + b * (N_ * 128);
#pragma unroll
  for (int mt = 0; mt < 7; ++mt)
#pragma unroll
    for (int j = 0; j < 4; ++j) {
      int node = mt * 16 + lg * 4 + j;
      bool ok = node < N_;
      pk0[mt][j] = ok ? pkp[node * 128 + d0] : 0u;
      pk1[mt][j] = ok ? pkp[node * 128 + d1] : 0u;
    }
  __syncthreads();

  bf16x8 bfr[2][2];
#pragma unroll
  for (int nt = 0; nt < 2; ++nt) {
    int d = w * 32 + nt * 16 + lr;
#pragma unroll
    for (int kb = 0; kb < 2; ++kb)
      bfr[nt][kb] = *(const bf16x8*)&wc_lds[d * 72 + kb * 32 + lg * 8];
  }

  float4 ld[7];
  {
    const float4* epf4 = (const float4*)(e + (size_t)(b * N_ + m0) * (N_ * ED_));
#pragma unroll
    for (int k = 0; k < 7; ++k) { int i = t + k * 256; if (i < 1600) ld[k] = epf4[i]; }
  }

  float s0 = 0.f, ss0 = 0.f, s1 = 0.f, ss1 = 0.f;
  int buf = 0;
  for (int r = 0; r < mcnt; ++r) {
#pragma unroll
    for (int k = 0; k < 7; ++k) {
      int i = t + k * 256;
      if (i < 1600) {
        float4 v = ld[k];
        int row = i >> 4, col = (i & 15) * 4;
        *(ushort4*)&e_lds[buf][row * 72 + col] =
            make_ushort4(f2bf(v.x), f2bf(v.y), f2bf(v.z), f2bf(v.w));
      }
    }
    __syncthreads();
    if (r + 1 < mcnt) {
      const float4* nxt = (const float4*)(e + (size_t)(b * N_ + m0 + r + 1) * (N_ * ED_));
#pragma unroll
      for (int k = 0; k < 7; ++k) { int i = t + k * 256; if (i < 1600) ld[k] = nxt[i]; }
    }

    const int bm = b * N_ + m0 + r;
    const float A0 = ws[WS_A + bm * 128 + d0];
    const float A1 = ws[WS_A + bm * 128 + d1];

    f32x4 acc[7][2];
#pragma unroll
    for (int mt = 0; mt < 7; ++mt) { acc[mt][0] = (f32x4)0.f; acc[mt][1] = (f32x4)0.f; }
#pragma unroll
    for (int mt = 0; mt < 7; ++mt) {
      int row = mt * 16 + lr;
      bf16x8 af0 = *(const bf16x8*)&e_lds[buf][row * 72 + lg * 8];
      bf16x8 af1 = *(const bf16x8*)&e_lds[buf][row * 72 + 32 + lg * 8];
#pragma unroll
      for (int nt = 0; nt < 2; ++nt) {
        acc[mt][nt] = MFMA16(af0, bfr[nt][0], acc[mt][nt]);
        acc[mt][nt] = MFMA16(af1, bfr[nt][1], acc[mt][nt]);
      }
    }

#pragma unroll
    for (int mt = 0; mt < 7; ++mt)
#pragma unroll
      for (int j = 0; j < 4; ++j) {
        int node = mt * 16 + lg * 4 + j;
        if (node < N_) {
          float x0 = acc[mt][0][j] + A0 + __uint_as_float(pk0[mt][j] << 16);
          float x1 = acc[mt][1][j] + A1 + __uint_as_float(pk1[mt][j] << 16);
          s0 += x0; ss0 += x0 * x0;
          s1 += x1; ss1 += x1 * x1;
        }
      }
    buf ^= 1;
  }

  s0 += __shfl_xor(s0, 16);  s0 += __shfl_xor(s0, 32);
  ss0 += __shfl_xor(ss0, 16); ss0 += __shfl_xor(ss0, 32);
  s1 += __shfl_xor(s1, 16);  s1 += __shfl_xor(s1, 32);
  ss1 += __shfl_xor(ss1, 16); ss1 += __shfl_xor(ss1, 32);
  if (l < 16) {
    atomicAdd(&ws[WS_STATS + b * 256 + d0], s0);
    atomicAdd(&ws[WS_STATS + b * 256 + 128 + d0], ss0);
    atomicAdd(&ws[WS_STATS + b * 256 + d1], s1);
    atomicAdd(&ws[WS_STATS + b * 256 + 128 + d1], ss1);
  }
}

// ---------------------------------------------------------------------------
// K0: finalize edge BN -> scale/shift (one block, 128 threads)
// ---------------------------------------------------------------------------
__global__ __launch_bounds__(128) void k0_finalize(
    const float* __restrict__ gamma_e, const float* __restrict__ beta_e,
    float* __restrict__ ws) {
  const int t = threadIdx.x;
  float S = 0.f, SS = 0.f;
#pragma unroll
  for (int j = 0; j < 32; ++j) {
    S  += ws[WS_STATS + j * 256 + t];
    SS += ws[WS_STATS + j * 256 + 128 + t];
  }
  float mean = S * (1.0f / EDGE_SAMPLES);
  float var  = SS * (1.0f / EDGE_SAMPLES) - mean * mean;
  float sc   = gamma_e[t] * rsqrtf(var + EPS_);
  ws[WS_SCSH + t]       = sc;
  ws[WS_SCSH + 128 + t] = beta_e[t] - mean * sc;
}

// ---------------------------------------------------------------------------
// K4: main fused pass. grid 3200, block 512 (8 waves; wave w owns d-cols
// [16w,16w+16)). R9 structure + ONE isolated change: bijective XCD-aware
// bm swizzle (bm = (bid&7)*400 + bid>>3; 3200 = 8*400) so the ~100 blocks
// sharing a batch b land on ONE XCD — its L2 then holds only 4 b-slices of
// pk/A (~400 KB) instead of all 32 (~3.2 MB), making the preamble's
// scattered pk loads L2 hits. Correctness unaffected (perf-only mapping).
// ---------------------------------------------------------------------------
__global__ __launch_bounds__(512) void k4_main(
    const float* __restrict__ e, const float* __restrict__ adj,
    const float* __restrict__ WC,
    float* __restrict__ ws, float* __restrict__ out_enorm) {
  __shared__ unsigned short e_lds[112 * 72];   // 15.75 KB
  __shared__ float adj_lds[112];
  const int t  = threadIdx.x;
  const int bm = (blockIdx.x & 7) * 400 + (blockIdx.x >> 3);  // XCD swizzle
  const int b  = bm / N_;
  const int w  = t >> 6;
  const int l  = t & 63;
  const int lr = l & 15;
  const int lg = l >> 4;
  const int d0 = w * 16 + lr;

  // (1) issue e loads
  float4 ld[4];
  const float4* ef4 = (const float4*)(e + (size_t)bm * (N_ * ED_));
#pragma unroll
  for (int k = 0; k < 4; ++k) { int i = t + k * 512; if (i < 1600) ld[k] = ef4[i]; }

  // (2) issue independent preloads: packed Bv/hnb, A, scale/shift, WC frags
  unsigned int pk[7][4];
  const unsigned int* pkp = (const unsigned int*)(ws + WS_PK) + b * (N_ * 128);
#pragma unroll
  for (int mt = 0; mt < 7; ++mt)
#pragma unroll
    for (int j = 0; j < 4; ++j) {
      int node = mt * 16 + lg * 4 + j;
      pk[mt][j] = (node < N_) ? pkp[node * 128 + d0] : 0u;
    }
  const float A0  = ws[WS_A + bm * 128 + d0];
  const float sc0 = ws[WS_SCSH + d0];
  const float sh0 = ws[WS_SCSH + 128 + d0];

  bf16x8 bfr[2];
#pragma unroll
  for (int kb = 0; kb < 2; ++kb) {
    const float* wrow = WC + d0 * 64 + kb * 32 + lg * 8;
    float4 u0 = *(const float4*)wrow;
    float4 u1 = *(const float4*)(wrow + 4);
    bf16x8 f;
    f[0] = (short)f2bf(u0.x); f[1] = (short)f2bf(u0.y);
    f[2] = (short)f2bf(u0.z); f[3] = (short)f2bf(u0.w);
    f[4] = (short)f2bf(u1.x); f[5] = (short)f2bf(u1.y);
    f[6] = (short)f2bf(u1.z); f[7] = (short)f2bf(u1.w);
    bfr[kb] = f;
  }

  if (t < 112) adj_lds[t] = (t < N_) ? adj[bm * N_ + t] : 0.f;

  // (3) stage e -> LDS (bf16)
#pragma unroll
  for (int k = 0; k < 4; ++k) {
    int i = t + k * 512;
    if (i < 1600) {
      float4 v = ld[k];
      int row = i >> 4, col = (i & 15) * 4;
      *(ushort4*)&e_lds[row * 72 + col] =
          make_ushort4(f2bf(v.x), f2bf(v.y), f2bf(v.z), f2bf(v.w));
    }
  }
  for (int i = t; i < 12 * 72; i += 512) e_lds[100 * 72 + i] = 0;
  __syncthreads();

  // (4) GEMM: 14 MFMAs per wave
  f32x4 acc[7];
#pragma unroll
  for (int mt = 0; mt < 7; ++mt) acc[mt] = (f32x4)0.f;
#pragma unroll
  for (int mt = 0; mt < 7; ++mt) {
    int row = mt * 16 + lr;
    bf16x8 af0 = *(const bf16x8*)&e_lds[row * 72 + lg * 8];
    bf16x8 af1 = *(const bf16x8*)&e_lds[row * 72 + 32 + lg * 8];
    acc[mt] = MFMA16(af0, bfr[0], acc[mt]);
    acc[mt] = MFMA16(af1, bfr[1], acc[mt]);
  }

  // (5) epilogue: BN -> relu -> *adj -> sigmoid -> exp (no predication)
  float den = 0.f;
#pragma unroll
  for (int mt = 0; mt < 7; ++mt)
#pragma unroll
    for (int j = 0; j < 4; ++j) {
      int node = mt * 16 + lg * 4 + j;
      float bv = __uint_as_float(pk[mt][j] << 16);
      float x  = (acc[mt][j] + A0 + bv) * sc0 + sh0;
      float r  = fmaxf(x, 0.f) * adj_lds[node];
      float en = __builtin_amdgcn_exp2f(r * -LOG2E_);
      float sg = __builtin_amdgcn_rcpf(1.f + en);
      float p  = __builtin_amdgcn_exp2f(sg * LOG2E_);
      acc[mt][j] = p; den += p;
    }
  den += __shfl_xor(den, 16); den += __shfl_xor(den, 32);
  // pad rows (zero e, adj=0) each contributed exactly exp2(0.5*log2e)
  den -= 12.f * __builtin_amdgcn_exp2f(0.5f * LOG2E_);
  const float rc = __builtin_amdgcn_rcpf(den);

  // (6) normalize, write e_norm, aggregate m
  float msg = 0.f;
  float* outp = out_enorm + (size_t)bm * (N_ * 128);
#pragma unroll
  for (int mt = 0; mt < 7; ++mt)
#pragma unroll
    for (int j = 0; j < 4; ++j) {
      int node = mt * 16 + lg * 4 + j;
      if (node < N_) {
        float v = acc[mt][j] * rc;
        outp[node * 128 + d0] = v;
        float hn = __uint_as_float(pk[mt][j] & 0xffff0000u);
        msg += v * hn;
      }
    }
  msg += __shfl_xor(msg, 16); msg += __shfl_xor(msg, 32);
  if (l < 16) {
    ws[WS_M + bm * 128 + d0] = msg;
    atomicAdd(&ws[WS_NSTB + b * 256 + d0],       msg);
    atomicAdd(&ws[WS_NSTB + b * 256 + 128 + d0], msg * msg);
  }
}

// ---------------------------------------------------------------------------
// K5b: finalize node BN (32-slot reduce) + h_out. grid 1600, block 256.
// ---------------------------------------------------------------------------
__global__ __launch_bounds__(256) void k5b_hout(
    const float* __restrict__ gamma_n, const float* __restrict__ beta_n,
    const float* __restrict__ ws, float* __restrict__ hout) {
  __shared__ float sc_l[128], sh_l[128];
  const int t = threadIdx.x;
  if (t < 128) {
    float S = 0.f, SS = 0.f;
#pragma unroll
    for (int j = 0; j < 32; ++j) {
      S  += ws[WS_NSTB + j * 256 + t];
      SS += ws[WS_NSTB + j * 256 + 128 + t];
    }
    float mean = S * (1.0f / (float)NNODE);
    float var  = SS * (1.0f / (float)NNODE) - mean * mean;
    float sc   = gamma_n[t] * rsqrtf(var + EPS_);
    sc_l[t] = sc;
    sh_l[t] = beta_n[t] - mean * sc;
  }
  __syncthreads();
  const int idx = blockIdx.x * 256 + t;   // < 409600
  const int d = t & 127;
  float mv = ws[WS_M + idx];
  hout[idx] = ws[WS_HIN + idx] + fmaxf(mv * sc_l[d] + sh_l[d], 0.f);
}

// ---------------------------------------------------------------------------
extern "C" void kernel_launch(void* const* d_in, const int* in_sizes, int n_in,
                              void* d_out, int out_size, void* d_ws, size_t ws_size,
                              hipStream_t stream) {
  (void)in_sizes; (void)n_in; (void)out_size; (void)ws_size;
  const float* h   = (const float*)d_in[0];
  const float* e   = (const float*)d_in[1];
  const float* adj = (const float*)d_in[2];
  const float* WU  = (const float*)d_in[3];
  const float* WV  = (const float*)d_in[4];
  const float* WA  = (const float*)d_in[5];
  const float* WB  = (const float*)d_in[6];
  const float* WC  = (const float*)d_in[7];
  const float* geg = (const float*)d_in[8];
  const float* geb = (const float*)d_in[9];
  const float* gng = (const float*)d_in[10];
  const float* gnb = (const float*)d_in[11];

  float* out = (float*)d_out;   // h_out [409600] then e_norm [40960000]
  float* ws  = (float*)d_ws;

  k1_proj    <<<dim3(25, 4),  256, 0, stream>>>(h, WA, WB, WU, WV, ws);
  k2_stats   <<<dim3(32, 15), 256, 0, stream>>>(e, WC, ws);
  k0_finalize<<<1,            128, 0, stream>>>(geg, geb, ws);
  k4_main    <<<3200,         512, 0, stream>>>(e, adj, WC, ws, out + 409600);
  k5b_hout   <<<1600,         256, 0, stream>>>(gng, gnb, ws, out);
}